// Round 1
// baseline (836.014 us; speedup 1.0000x reference)
//
#include <hip/hip_runtime.h>
#include <math.h>

#define NB 8
#define NC 192
#define NH 56
#define NW 56
#define NN 3136      // NH*NW
#define NK 16        // clusters
#define KNB 9        // neighbors
#define NCOUT 384    // 2*NC

#define FLT_INF __builtin_inff()

__device__ __forceinline__ float gelu_t(float x) {
    const float k0 = 0.7978845608028654f;
    float u = k0 * (x + 0.044715f * x * x * x);
    float t = tanhf(u);
    return 0.5f * x * (1.0f + t);
}

// ---------------- histogram + offsets ----------------
__global__ void hist_kernel(const int* __restrict__ labels, int* __restrict__ cntk,
                            int* __restrict__ offk) {
    __shared__ int h[NK];
    int b = blockIdx.x;
    if (threadIdx.x < NK) h[threadIdx.x] = 0;
    __syncthreads();
    for (int n = threadIdx.x; n < NN; n += blockDim.x)
        atomicAdd(&h[labels[b * NN + n] & 15], 1);
    __syncthreads();
    if (threadIdx.x == 0) {
        int run = 0;
        for (int k = 0; k < NK; ++k) {
            offk[b * NK + k] = run;
            cntk[b * NK + k] = h[k];
            run += h[k];
        }
    }
}

// ---------------- stable counting sort: order / mapping / sorted labels ----------------
__global__ void order_kernel(const int* __restrict__ labels, const int* __restrict__ offk,
                             int* __restrict__ order, int* __restrict__ mapping,
                             int* __restrict__ lsv) {
    int b = blockIdx.x >> 4;
    int k = blockIdx.x & 15;
    int lane = threadIdx.x;  // 64 threads
    int base = offk[b * NK + k];
    int run = 0;
    for (int n0 = 0; n0 < NN; n0 += 64) {
        int n = n0 + lane;
        int lab = (n < NN) ? labels[b * NN + n] : -1;
        bool p = (lab == k);
        unsigned long long mask = __ballot(p);
        int rank = __popcll(mask & ((1ull << lane) - 1ull));
        if (p) {
            int pos = base + run + rank;
            order[b * NN + pos] = n;
            mapping[b * NN + n] = pos;
            lsv[b * NN + pos] = k;
        }
        run += __popcll(mask);
    }
}

// ---------------- depthwise 7x7 conv + bias + residual ----------------
__global__ __launch_bounds__(256) void conv_kernel(const float* __restrict__ X,
                                                   const float* __restrict__ W7,
                                                   const float* __restrict__ bias,
                                                   float* __restrict__ xpe) {
    __shared__ float tile[62 * 62];
    __shared__ float wl[49];
    int bc = blockIdx.x;  // b*NC + c
    int c = bc % NC;
    const float* Xp = X + (size_t)bc * NN;
    int tid = threadIdx.x;
    if (tid < 49) wl[tid] = W7[(size_t)c * 49 + tid];
    for (int idx = tid; idx < 62 * 62; idx += 256) {
        int ty = idx / 62, tx = idx % 62;
        int gy = ty - 3, gx = tx - 3;
        float v = 0.0f;
        if (gy >= 0 && gy < NH && gx >= 0 && gx < NW) v = Xp[gy * NW + gx];
        tile[idx] = v;
    }
    __syncthreads();
    float cb = bias[c];
    for (int p = tid; p < NN; p += 256) {
        int y = p / NW, x = p % NW;
        float acc = 0.0f;
#pragma unroll
        for (int dy = 0; dy < 7; ++dy)
#pragma unroll
            for (int dx = 0; dx < 7; ++dx)
                acc += tile[(y + dy) * 62 + (x + dx)] * wl[dy * 7 + dx];
        xpe[(size_t)bc * NN + p] = acc + cb + tile[(y + 3) * 62 + x + 3];
    }
}

// ---------------- generic tiled fp32 GEMM, 64x64 tiles, BK=16 ----------------
// AT: A stored [K][M] (lda = row length = M-ish); else A stored [M][K] (lda = K-ish)
// B stored [K][Ncols] (ldb). Output row m goes to rowmap[b*M+m] if rowmap != null.
template <bool AT>
__global__ __launch_bounds__(256) void gemm64(const float* __restrict__ A, size_t aStride,
                                              int lda, const float* __restrict__ Bm, int ldb,
                                              const float* __restrict__ bias,
                                              float* __restrict__ Co, size_t cStride, int ldc,
                                              const int* __restrict__ rowmap, int M, int Kd) {
    __shared__ float As[16 * 64];
    __shared__ float Bs[16 * 64];
    int b = blockIdx.z;
    int m0 = blockIdx.y * 64;
    int n0 = blockIdx.x * 64;
    const float* Ab = A + (size_t)b * aStride;
    int tid = threadIdx.x;
    int tm = tid / 16, tn = tid % 16;
    float acc[4][4] = {};
    for (int kc = 0; kc < Kd; kc += 16) {
        if (AT) {
            int kk = tid / 16;
            int mm = (tid % 16) * 4;
            float4 av = *(const float4*)(Ab + (size_t)(kc + kk) * lda + m0 + mm);
            *(float4*)(As + kk * 64 + mm) = av;
        } else {
            int mm = tid / 4;
            int k4 = (tid % 4) * 4;
            float4 av = *(const float4*)(Ab + (size_t)(m0 + mm) * lda + kc + k4);
            As[(k4 + 0) * 64 + mm] = av.x;
            As[(k4 + 1) * 64 + mm] = av.y;
            As[(k4 + 2) * 64 + mm] = av.z;
            As[(k4 + 3) * 64 + mm] = av.w;
        }
        {
            int kk = tid / 16;
            int nn = (tid % 16) * 4;
            float4 bv = *(const float4*)(Bm + (size_t)(kc + kk) * ldb + n0 + nn);
            *(float4*)(Bs + kk * 64 + nn) = bv;
        }
        __syncthreads();
#pragma unroll
        for (int kk = 0; kk < 16; ++kk) {
            float4 a4 = *(const float4*)(As + kk * 64 + tm * 4);
            float4 b4 = *(const float4*)(Bs + kk * 64 + tn * 4);
            float aa[4] = {a4.x, a4.y, a4.z, a4.w};
            float bb[4] = {b4.x, b4.y, b4.z, b4.w};
#pragma unroll
            for (int i = 0; i < 4; ++i)
#pragma unroll
                for (int j = 0; j < 4; ++j) acc[i][j] += aa[i] * bb[j];
        }
        __syncthreads();
    }
    float* Cb = Co + (size_t)b * cStride;
#pragma unroll
    for (int i = 0; i < 4; ++i) {
        int m = m0 + tm * 4 + i;
        int row = rowmap ? rowmap[(size_t)b * M + m] : m;
        float4 v;
        v.x = acc[i][0];
        v.y = acc[i][1];
        v.z = acc[i][2];
        v.w = acc[i][3];
        if (bias) {
            v.x += bias[n0 + tn * 4 + 0];
            v.y += bias[n0 + tn * 4 + 1];
            v.z += bias[n0 + tn * 4 + 2];
            v.w += bias[n0 + tn * 4 + 3];
        }
        *(float4*)(Cb + (size_t)row * ldc + n0 + tn * 4) = v;
    }
}

// ---------------- per-row 1/norm and sum(xe^2) ----------------
__global__ void norm_kernel(const float* __restrict__ xs, float* __restrict__ rinv,
                            float* __restrict__ sqv) {
    int row = blockIdx.x * 4 + (threadIdx.x >> 6);
    int lane = threadIdx.x & 63;
    const float* p = xs + (size_t)row * NC;
    float v0 = p[lane], v1 = p[lane + 64], v2 = p[lane + 128];
    float s = v0 * v0 + v1 * v1 + v2 * v2;
#pragma unroll
    for (int m = 32; m; m >>= 1) s += __shfl_xor(s, m, 64);
    float nrm = fmaxf(sqrtf(s), 1e-12f);
    float ri = 1.0f / nrm;
    float e0 = v0 * ri, e1 = v1 * ri, e2 = v2 * ri;
    float s2 = e0 * e0 + e1 * e1 + e2 * e2;
#pragma unroll
    for (int m = 32; m; m >>= 1) s2 += __shfl_xor(s2, m, 64);
    if (lane == 0) {
        rinv[row] = ri;
        sqv[row] = s2;
    }
}

// ---------------- per-cluster pairwise distances + top-9 ----------------
__global__ __launch_bounds__(256) void knn_kernel(const float* __restrict__ xs,
                                                  const float* __restrict__ rinv,
                                                  const float* __restrict__ sqv,
                                                  const int* __restrict__ offk,
                                                  const int* __restrict__ cntk,
                                                  int* __restrict__ nbr) {
    __shared__ float As[64 * 64];  // [k][i]
    __shared__ float Bs[64 * 64];  // [k][j]
    __shared__ float Ds[64 * 65];  // [i][j]
    int b = blockIdx.x >> 4;
    int k = blockIdx.x & 15;
    int base = offk[b * NK + k];
    int L = cntk[b * NK + k];
    if (L <= 0) return;
    const float* Xb = xs + (size_t)b * NN * NC;
    const float* Rb = rinv + (size_t)b * NN;
    const float* Sb = sqv + (size_t)b * NN;
    int tid = threadIdx.x;
    int tm = tid % 16, tn = tid / 16;
    int lr = tid / 4;          // load row 0..63
    int lc = (tid % 4) * 16;   // load col base (k dim)

    for (int i0 = 0; i0 < L; i0 += 64) {
        float d9[KNB];
        int x9[KNB];
#pragma unroll
        for (int q = 0; q < KNB; ++q) {
            d9[q] = FLT_INF;
            x9[q] = -1;
        }
        for (int j0 = 0; j0 < L; j0 += 64) {
            float acc[4][4] = {};
            for (int kc = 0; kc < NC; kc += 64) {
                __syncthreads();
                {
                    int ri = i0 + lr;
                    ri = ri < L ? ri : L - 1;
                    float rv = Rb[base + ri];
                    const float* src = Xb + (size_t)(base + ri) * NC + kc + lc;
                    int rj = j0 + lr;
                    rj = rj < L ? rj : L - 1;
                    float rvj = Rb[base + rj];
                    const float* srcj = Xb + (size_t)(base + rj) * NC + kc + lc;
#pragma unroll
                    for (int q4 = 0; q4 < 16; q4 += 4) {
                        float4 v = *(const float4*)(src + q4);
                        As[(lc + q4 + 0) * 64 + lr] = v.x * rv;
                        As[(lc + q4 + 1) * 64 + lr] = v.y * rv;
                        As[(lc + q4 + 2) * 64 + lr] = v.z * rv;
                        As[(lc + q4 + 3) * 64 + lr] = v.w * rv;
                        float4 w = *(const float4*)(srcj + q4);
                        Bs[(lc + q4 + 0) * 64 + lr] = w.x * rvj;
                        Bs[(lc + q4 + 1) * 64 + lr] = w.y * rvj;
                        Bs[(lc + q4 + 2) * 64 + lr] = w.z * rvj;
                        Bs[(lc + q4 + 3) * 64 + lr] = w.w * rvj;
                    }
                }
                __syncthreads();
#pragma unroll
                for (int kk = 0; kk < 64; ++kk) {
                    float4 a4 = *(const float4*)(As + kk * 64 + tm * 4);
                    float4 b4 = *(const float4*)(Bs + kk * 64 + tn * 4);
                    float aa[4] = {a4.x, a4.y, a4.z, a4.w};
                    float bb[4] = {b4.x, b4.y, b4.z, b4.w};
#pragma unroll
                    for (int i = 0; i < 4; ++i)
#pragma unroll
                        for (int j = 0; j < 4; ++j) acc[i][j] += aa[i] * bb[j];
                }
            }
            __syncthreads();
#pragma unroll
            for (int i = 0; i < 4; ++i) {
                int ii = i0 + tm * 4 + i;
                float si = (ii < L) ? Sb[base + ii] : 0.0f;
#pragma unroll
                for (int j = 0; j < 4; ++j) {
                    int jj = j0 + tn * 4 + j;
                    float d = (ii < L && jj < L) ? (si + Sb[base + jj] - 2.0f * acc[i][j])
                                                 : FLT_INF;
                    Ds[(tm * 4 + i) * 65 + tn * 4 + j] = d;
                }
            }
            __syncthreads();
            if (tid < 64) {
                int r = tid;
                if (i0 + r < L) {
                    int jmax = (L - j0) < 64 ? (L - j0) : 64;
                    for (int jc = 0; jc < jmax; ++jc) {
                        float d = Ds[r * 65 + jc];
                        if (d < d9[KNB - 1]) {
                            d9[KNB - 1] = d;
                            x9[KNB - 1] = base + j0 + jc;
#pragma unroll
                            for (int q = KNB - 1; q > 0; --q) {
                                if (d9[q] < d9[q - 1]) {
                                    float td = d9[q];
                                    d9[q] = d9[q - 1];
                                    d9[q - 1] = td;
                                    int ti = x9[q];
                                    x9[q] = x9[q - 1];
                                    x9[q - 1] = ti;
                                }
                            }
                        }
                    }
                }
            }
        }
        if (tid < 64 && i0 + tid < L) {
            size_t row = (size_t)b * NN + base + i0 + tid;
#pragma unroll
            for (int q = 0; q < KNB; ++q) nbr[row * KNB + q] = x9[q];
        }
    }
}

// ---------------- centroids ----------------
__global__ void cen_kernel(const float* __restrict__ xs, const int* __restrict__ offk,
                           const int* __restrict__ cntk, float* __restrict__ cen) {
    int b = blockIdx.x >> 4, k = blockIdx.x & 15;
    int base = offk[b * NK + k], L = cntk[b * NK + k];
    int c = threadIdx.x;  // 192
    float s = 0.0f;
    for (int r = 0; r < L; ++r) s += xs[((size_t)b * NN + base + r) * NC + c];
    cen[((size_t)b * NK + k) * NC + c] = s / fmaxf((float)L, 1.0f);
}

// ---------------- cluster P/Q ----------------
__global__ __launch_bounds__(384) void pcqc_kernel(const float* __restrict__ cen,
                                                   const float* __restrict__ Wc,
                                                   const float* __restrict__ bc,
                                                   float* __restrict__ Pc,
                                                   float* __restrict__ Qc) {
    __shared__ float ce[NC];
    int bk = blockIdx.x;
    int o = threadIdx.x;  // 384
    if (o < NC) ce[o] = cen[(size_t)bk * NC + o];
    __syncthreads();
    float pc = bc[o], qc = 0.0f;
    for (int c = 0; c < NC; ++c) {
        pc += ce[c] * Wc[(size_t)c * NCOUT + o];
        qc += ce[c] * Wc[(size_t)(NC + c) * NCOUT + o];
    }
    Pc[(size_t)bk * NCOUT + o] = pc;
    Qc[(size_t)bk * NCOUT + o] = qc;
}

// ---------------- cluster message max ----------------
__global__ __launch_bounds__(384) void hcmax_kernel(const float* __restrict__ Pc,
                                                    const float* __restrict__ Qc,
                                                    float* __restrict__ hc) {
    int b = blockIdx.x >> 4, i = blockIdx.x & 15;
    int o = threadIdx.x;
    float pi = Pc[((size_t)b * NK + i) * NCOUT + o];
    float qi = Qc[((size_t)b * NK + i) * NCOUT + o];
    float m = -FLT_INF;
    for (int j = 0; j < NK; ++j) {
        float z = pi - qi + Qc[((size_t)b * NK + j) * NCOUT + o];
        m = fmaxf(m, gelu_t(z));
    }
    hc[((size_t)b * NK + i) * NCOUT + o] = m;
}

// ---------------- node message max + add cluster term (writes hn over P) ----------------
__global__ __launch_bounds__(384) void hv_kernel(float* __restrict__ P,
                                                 const float* __restrict__ Q,
                                                 const int* __restrict__ nbr,
                                                 const int* __restrict__ lsv,
                                                 const float* __restrict__ hc) {
    int i = blockIdx.x;
    int b = blockIdx.y;
    size_t row = (size_t)b * NN + i;
    int o = threadIdx.x;  // 384
    float pi = P[row * NCOUT + o];
    float qi = Q[row * NCOUT + o];
    float m = -FLT_INF;
#pragma unroll
    for (int q = 0; q < KNB; ++q) {
        int j = nbr[row * KNB + q];
        if (j < 0) break;
        float z = pi - qi + Q[((size_t)b * NN + j) * NCOUT + o];
        m = fmaxf(m, gelu_t(z));
    }
    int lab = lsv[row];
    P[row * NCOUT + o] = m + hc[((size_t)b * NK + lab) * NCOUT + o];
}

// ---------------- transpose (b,n,c)->(b,c,n) + residual ----------------
__global__ void out_kernel(const float* __restrict__ T, const float* __restrict__ X,
                           float* __restrict__ Y) {
    __shared__ float t[32][33];
    int b = blockIdx.z;
    int n0 = blockIdx.y * 32, c0 = blockIdx.x * 32;
    int tx = threadIdx.x, ty = threadIdx.y;  // 32 x 8
#pragma unroll
    for (int q = 0; q < 4; ++q) {
        int n = n0 + ty + q * 8;
        t[ty + q * 8][tx] = T[((size_t)b * NN + n) * NC + c0 + tx];
    }
    __syncthreads();
#pragma unroll
    for (int q = 0; q < 4; ++q) {
        int c = c0 + ty + q * 8;
        size_t idx = ((size_t)b * NC + c) * NN + n0 + tx;
        Y[idx] = t[tx][ty + q * 8] + X[idx];
    }
}

extern "C" void kernel_launch(void* const* d_in, const int* in_sizes, int n_in, void* d_out,
                              int out_size, void* d_ws, size_t ws_size, hipStream_t stream) {
    const float* x = (const float*)d_in[0];
    const int* labels = (const int*)d_in[1];
    const float* cpe_w = (const float*)d_in[2];
    const float* cpe_b = (const float*)d_in[3];
    const float* fc1_w = (const float*)d_in[4];
    const float* fc1_b = (const float*)d_in[5];
    const float* nn_v_w = (const float*)d_in[6];
    const float* nn_v_b = (const float*)d_in[7];
    const float* nn_c_w = (const float*)d_in[8];
    const float* nn_c_b = (const float*)d_in[9];
    const float* fc2_w = (const float*)d_in[10];
    const float* fc2_b = (const float*)d_in[11];
    float* out = (float*)d_out;

    const size_t SZ_XS = (size_t)NB * NN * NC;     // 4,816,896
    const size_t SZ_P = (size_t)NB * NN * NCOUT;   // 9,633,792
    const size_t BN = (size_t)NB * NN;             // 25,088
    const size_t SZ_CEN = (size_t)NB * NK * NC;    // 24,576
    const size_t SZ_PC = (size_t)NB * NK * NCOUT;  // 49,152

    float* base = (float*)d_ws;
    float* xs = base;
    float* xpe = xs + SZ_XS;     // also reused as out_t after fc1
    float* Pb = xpe + SZ_XS;     // also becomes hn in-place
    float* Qb = Pb + SZ_P;
    float* rinv = Qb + SZ_P;
    float* sqv = rinv + BN;
    float* cen = sqv + BN;
    float* Pc = cen + SZ_CEN;
    float* Qc = Pc + SZ_PC;
    float* hcv = Qc + SZ_PC;
    int* order = (int*)(hcv + SZ_PC);
    int* mapping = order + BN;
    int* lsv = mapping + BN;
    int* nbrv = lsv + BN;
    int* cntk = nbrv + BN * KNB;
    int* offk = cntk + NB * NK;

    hist_kernel<<<NB, 256, 0, stream>>>(labels, cntk, offk);
    order_kernel<<<NB * NK, 64, 0, stream>>>(labels, offk, order, mapping, lsv);
    conv_kernel<<<NB * NC, 256, 0, stream>>>(x, cpe_w, cpe_b, xpe);
    // fc1: xf = xpe^T @ fc1_w + b, rows scattered into sorted order (xs)
    gemm64<true><<<dim3(NC / 64, NN / 64, NB), 256, 0, stream>>>(
        xpe, (size_t)NC * NN, NN, fc1_w, NC, fc1_b, xs, (size_t)NN * NC, NC, mapping, NN, NC);
    norm_kernel<<<(NB * NN) / 4, 256, 0, stream>>>(xs, rinv, sqv);
    knn_kernel<<<NB * NK, 256, 0, stream>>>(xs, rinv, sqv, offk, cntk, nbrv);
    // P = xs @ Wv_top + bv ; Q = xs @ Wv_bot
    gemm64<false><<<dim3(NCOUT / 64, NN / 64, NB), 256, 0, stream>>>(
        xs, (size_t)NN * NC, NC, nn_v_w, NCOUT, nn_v_b, Pb, (size_t)NN * NCOUT, NCOUT, nullptr,
        NN, NC);
    gemm64<false><<<dim3(NCOUT / 64, NN / 64, NB), 256, 0, stream>>>(
        xs, (size_t)NN * NC, NC, nn_v_w + (size_t)NC * NCOUT, NCOUT, nullptr, Qb,
        (size_t)NN * NCOUT, NCOUT, nullptr, NN, NC);
    cen_kernel<<<NB * NK, NC, 0, stream>>>(xs, offk, cntk, cen);
    pcqc_kernel<<<NB * NK, NCOUT, 0, stream>>>(cen, nn_c_w, nn_c_b, Pc, Qc);
    hcmax_kernel<<<NB * NK, NCOUT, 0, stream>>>(Pc, Qc, hcv);
    hv_kernel<<<dim3(NN, NB), NCOUT, 0, stream>>>(Pb, Qb, nbrv, lsv, hcv);
    // fc2: out_t[order[i]] = hn[i] @ fc2_w + b
    gemm64<false><<<dim3(NC / 64, NN / 64, NB), 256, 0, stream>>>(
        Pb, (size_t)NN * NCOUT, NCOUT, fc2_w, NC, fc2_b, xpe, (size_t)NN * NC, NC, order, NN,
        NCOUT);
    out_kernel<<<dim3(NC / 32, NN / 32, NB), dim3(32, 8), 0, stream>>>(xpe, x, out);
}

// Round 2
// 700.082 us; speedup vs baseline: 1.1942x; 1.1942x over previous
//
#include <hip/hip_runtime.h>
#include <math.h>

#define NB 8
#define NC 192
#define NH 56
#define NW 56
#define NN 3136      // NH*NW
#define NK 16        // clusters
#define KNB 9        // neighbors
#define NCOUT 384    // 2*NC

#define FLT_INF __builtin_inff()

__device__ __forceinline__ float gelu_t(float x) {
    const float k0 = 0.7978845608028654f;
    float u = k0 * (x + 0.044715f * x * x * x);
    float t = tanhf(u);
    return 0.5f * x * (1.0f + t);
}

// ---------------- histogram + offsets ----------------
__global__ void hist_kernel(const int* __restrict__ labels, int* __restrict__ cntk,
                            int* __restrict__ offk) {
    __shared__ int h[NK];
    int b = blockIdx.x;
    if (threadIdx.x < NK) h[threadIdx.x] = 0;
    __syncthreads();
    for (int n = threadIdx.x; n < NN; n += blockDim.x)
        atomicAdd(&h[labels[b * NN + n] & 15], 1);
    __syncthreads();
    if (threadIdx.x == 0) {
        int run = 0;
        for (int k = 0; k < NK; ++k) {
            offk[b * NK + k] = run;
            cntk[b * NK + k] = h[k];
            run += h[k];
        }
    }
}

// ---------------- stable counting sort: order / mapping / sorted labels ----------------
__global__ void order_kernel(const int* __restrict__ labels, const int* __restrict__ offk,
                             int* __restrict__ order, int* __restrict__ mapping,
                             int* __restrict__ lsv) {
    int b = blockIdx.x >> 4;
    int k = blockIdx.x & 15;
    int lane = threadIdx.x;  // 64 threads
    int base = offk[b * NK + k];
    int run = 0;
    for (int n0 = 0; n0 < NN; n0 += 64) {
        int n = n0 + lane;
        int lab = (n < NN) ? labels[b * NN + n] : -1;
        bool p = (lab == k);
        unsigned long long mask = __ballot(p);
        int rank = __popcll(mask & ((1ull << lane) - 1ull));
        if (p) {
            int pos = base + run + rank;
            order[b * NN + pos] = n;
            mapping[b * NN + n] = pos;
            lsv[b * NN + pos] = k;
        }
        run += __popcll(mask);
    }
}

// ---------------- depthwise 7x7 conv + bias + residual ----------------
__global__ __launch_bounds__(256) void conv_kernel(const float* __restrict__ X,
                                                   const float* __restrict__ W7,
                                                   const float* __restrict__ bias,
                                                   float* __restrict__ xpe) {
    __shared__ float tile[62 * 62];
    __shared__ float wl[49];
    int bc = blockIdx.x;  // b*NC + c
    int c = bc % NC;
    const float* Xp = X + (size_t)bc * NN;
    int tid = threadIdx.x;
    if (tid < 49) wl[tid] = W7[(size_t)c * 49 + tid];
    for (int idx = tid; idx < 62 * 62; idx += 256) {
        int ty = idx / 62, tx = idx % 62;
        int gy = ty - 3, gx = tx - 3;
        float v = 0.0f;
        if (gy >= 0 && gy < NH && gx >= 0 && gx < NW) v = Xp[gy * NW + gx];
        tile[idx] = v;
    }
    __syncthreads();
    float cb = bias[c];
    for (int p = tid; p < NN; p += 256) {
        int y = p / NW, x = p % NW;
        float acc = 0.0f;
#pragma unroll
        for (int dy = 0; dy < 7; ++dy)
#pragma unroll
            for (int dx = 0; dx < 7; ++dx)
                acc += tile[(y + dy) * 62 + (x + dx)] * wl[dy * 7 + dx];
        xpe[(size_t)bc * NN + p] = acc + cb + tile[(y + 3) * 62 + x + 3];
    }
}

// ---------------- generic tiled fp32 GEMM, 64x64 tiles, BK=16 ----------------
template <bool AT>
__global__ __launch_bounds__(256) void gemm64(const float* __restrict__ A, size_t aStride,
                                              int lda, const float* __restrict__ Bm, int ldb,
                                              const float* __restrict__ bias,
                                              float* __restrict__ Co, size_t cStride, int ldc,
                                              const int* __restrict__ rowmap, int M, int Kd) {
    __shared__ float As[16 * 64];
    __shared__ float Bs[16 * 64];
    int b = blockIdx.z;
    int m0 = blockIdx.y * 64;
    int n0 = blockIdx.x * 64;
    const float* Ab = A + (size_t)b * aStride;
    int tid = threadIdx.x;
    int tm = tid / 16, tn = tid % 16;
    float acc[4][4] = {};
    for (int kc = 0; kc < Kd; kc += 16) {
        if (AT) {
            int kk = tid / 16;
            int mm = (tid % 16) * 4;
            float4 av = *(const float4*)(Ab + (size_t)(kc + kk) * lda + m0 + mm);
            *(float4*)(As + kk * 64 + mm) = av;
        } else {
            int mm = tid / 4;
            int k4 = (tid % 4) * 4;
            float4 av = *(const float4*)(Ab + (size_t)(m0 + mm) * lda + kc + k4);
            As[(k4 + 0) * 64 + mm] = av.x;
            As[(k4 + 1) * 64 + mm] = av.y;
            As[(k4 + 2) * 64 + mm] = av.z;
            As[(k4 + 3) * 64 + mm] = av.w;
        }
        {
            int kk = tid / 16;
            int nn = (tid % 16) * 4;
            float4 bv = *(const float4*)(Bm + (size_t)(kc + kk) * ldb + n0 + nn);
            *(float4*)(Bs + kk * 64 + nn) = bv;
        }
        __syncthreads();
#pragma unroll
        for (int kk = 0; kk < 16; ++kk) {
            float4 a4 = *(const float4*)(As + kk * 64 + tm * 4);
            float4 b4 = *(const float4*)(Bs + kk * 64 + tn * 4);
            float aa[4] = {a4.x, a4.y, a4.z, a4.w};
            float bb[4] = {b4.x, b4.y, b4.z, b4.w};
#pragma unroll
            for (int i = 0; i < 4; ++i)
#pragma unroll
                for (int j = 0; j < 4; ++j) acc[i][j] += aa[i] * bb[j];
        }
        __syncthreads();
    }
    float* Cb = Co + (size_t)b * cStride;
#pragma unroll
    for (int i = 0; i < 4; ++i) {
        int m = m0 + tm * 4 + i;
        int row = rowmap ? rowmap[(size_t)b * M + m] : m;
        float4 v;
        v.x = acc[i][0];
        v.y = acc[i][1];
        v.z = acc[i][2];
        v.w = acc[i][3];
        if (bias) {
            v.x += bias[n0 + tn * 4 + 0];
            v.y += bias[n0 + tn * 4 + 1];
            v.z += bias[n0 + tn * 4 + 2];
            v.w += bias[n0 + tn * 4 + 3];
        }
        *(float4*)(Cb + (size_t)row * ldc + n0 + tn * 4) = v;
    }
}

// ---------------- per-row 1/norm and sum(xe^2) ----------------
__global__ void norm_kernel(const float* __restrict__ xs, float* __restrict__ rinv,
                            float* __restrict__ sqv) {
    int row = blockIdx.x * 4 + (threadIdx.x >> 6);
    int lane = threadIdx.x & 63;
    const float* p = xs + (size_t)row * NC;
    float v0 = p[lane], v1 = p[lane + 64], v2 = p[lane + 128];
    float s = v0 * v0 + v1 * v1 + v2 * v2;
#pragma unroll
    for (int m = 32; m; m >>= 1) s += __shfl_xor(s, m, 64);
    float nrm = fmaxf(sqrtf(s), 1e-12f);
    float ri = 1.0f / nrm;
    float e0 = v0 * ri, e1 = v1 * ri, e2 = v2 * ri;
    float s2 = e0 * e0 + e1 * e1 + e2 * e2;
#pragma unroll
    for (int m = 32; m; m >>= 1) s2 += __shfl_xor(s2, m, 64);
    if (lane == 0) {
        rinv[row] = ri;
        sqv[row] = s2;
    }
}

// ---------------- per-cluster pairwise distances + top-9 ----------------
// Parallelized over i-tiles: grid = (ceil(NN/64), NK, NB). Blocks with
// i0 >= L exit immediately (~512 of 6272 stay active; fixes the 4.8%
// occupancy seen in round 1).
__global__ __launch_bounds__(256) void knn_kernel(const float* __restrict__ xs,
                                                  const float* __restrict__ rinv,
                                                  const float* __restrict__ sqv,
                                                  const int* __restrict__ offk,
                                                  const int* __restrict__ cntk,
                                                  int* __restrict__ nbr) {
    __shared__ float As[64 * 64];  // [k][i]
    __shared__ float Bs[64 * 64];  // [k][j]
    __shared__ float Ds[64 * 65];  // [i][j]
    int b = blockIdx.z;
    int k = blockIdx.y;
    int base = offk[b * NK + k];
    int L = cntk[b * NK + k];
    int i0 = blockIdx.x * 64;
    if (i0 >= L) return;
    const float* Xb = xs + (size_t)b * NN * NC;
    const float* Rb = rinv + (size_t)b * NN;
    const float* Sb = sqv + (size_t)b * NN;
    int tid = threadIdx.x;
    int tm = tid % 16, tn = tid / 16;
    int lr = tid / 4;          // load row 0..63
    int lc = (tid % 4) * 16;   // load col base (k dim)

    float d9[KNB];
    int x9[KNB];
#pragma unroll
    for (int q = 0; q < KNB; ++q) {
        d9[q] = FLT_INF;
        x9[q] = -1;
    }
    for (int j0 = 0; j0 < L; j0 += 64) {
        float acc[4][4] = {};
        for (int kc = 0; kc < NC; kc += 64) {
            __syncthreads();
            {
                int ri = i0 + lr;
                ri = ri < L ? ri : L - 1;
                float rv = Rb[base + ri];
                const float* src = Xb + (size_t)(base + ri) * NC + kc + lc;
                int rj = j0 + lr;
                rj = rj < L ? rj : L - 1;
                float rvj = Rb[base + rj];
                const float* srcj = Xb + (size_t)(base + rj) * NC + kc + lc;
#pragma unroll
                for (int q4 = 0; q4 < 16; q4 += 4) {
                    float4 v = *(const float4*)(src + q4);
                    As[(lc + q4 + 0) * 64 + lr] = v.x * rv;
                    As[(lc + q4 + 1) * 64 + lr] = v.y * rv;
                    As[(lc + q4 + 2) * 64 + lr] = v.z * rv;
                    As[(lc + q4 + 3) * 64 + lr] = v.w * rv;
                    float4 w = *(const float4*)(srcj + q4);
                    Bs[(lc + q4 + 0) * 64 + lr] = w.x * rvj;
                    Bs[(lc + q4 + 1) * 64 + lr] = w.y * rvj;
                    Bs[(lc + q4 + 2) * 64 + lr] = w.z * rvj;
                    Bs[(lc + q4 + 3) * 64 + lr] = w.w * rvj;
                }
            }
            __syncthreads();
#pragma unroll
            for (int kk = 0; kk < 64; ++kk) {
                float4 a4 = *(const float4*)(As + kk * 64 + tm * 4);
                float4 b4 = *(const float4*)(Bs + kk * 64 + tn * 4);
                float aa[4] = {a4.x, a4.y, a4.z, a4.w};
                float bb[4] = {b4.x, b4.y, b4.z, b4.w};
#pragma unroll
                for (int i = 0; i < 4; ++i)
#pragma unroll
                    for (int j = 0; j < 4; ++j) acc[i][j] += aa[i] * bb[j];
            }
        }
        __syncthreads();
#pragma unroll
        for (int i = 0; i < 4; ++i) {
            int ii = i0 + tm * 4 + i;
            float si = (ii < L) ? Sb[base + ii] : 0.0f;
#pragma unroll
            for (int j = 0; j < 4; ++j) {
                int jj = j0 + tn * 4 + j;
                float d = (ii < L && jj < L) ? (si + Sb[base + jj] - 2.0f * acc[i][j])
                                             : FLT_INF;
                Ds[(tm * 4 + i) * 65 + tn * 4 + j] = d;
            }
        }
        __syncthreads();
        if (tid < 64) {
            int r = tid;
            if (i0 + r < L) {
                int jmax = (L - j0) < 64 ? (L - j0) : 64;
                for (int jc = 0; jc < jmax; ++jc) {
                    float d = Ds[r * 65 + jc];
                    if (d < d9[KNB - 1]) {
                        d9[KNB - 1] = d;
                        x9[KNB - 1] = base + j0 + jc;
#pragma unroll
                        for (int q = KNB - 1; q > 0; --q) {
                            if (d9[q] < d9[q - 1]) {
                                float td = d9[q];
                                d9[q] = d9[q - 1];
                                d9[q - 1] = td;
                                int ti = x9[q];
                                x9[q] = x9[q - 1];
                                x9[q - 1] = ti;
                            }
                        }
                    }
                }
            }
        }
    }
    if (tid < 64 && i0 + tid < L) {
        size_t row = (size_t)b * NN + base + i0 + tid;
#pragma unroll
        for (int q = 0; q < KNB; ++q) nbr[row * KNB + q] = x9[q];
    }
}

// ---------------- centroids ----------------
__global__ void cen_kernel(const float* __restrict__ xs, const int* __restrict__ offk,
                           const int* __restrict__ cntk, float* __restrict__ cen) {
    int b = blockIdx.x >> 4, k = blockIdx.x & 15;
    int base = offk[b * NK + k], L = cntk[b * NK + k];
    int c = threadIdx.x;  // 192
    float s = 0.0f;
    for (int r = 0; r < L; ++r) s += xs[((size_t)b * NN + base + r) * NC + c];
    cen[((size_t)b * NK + k) * NC + c] = s / fmaxf((float)L, 1.0f);
}

// ---------------- cluster P/Q ----------------
__global__ __launch_bounds__(384) void pcqc_kernel(const float* __restrict__ cen,
                                                   const float* __restrict__ Wc,
                                                   const float* __restrict__ bc,
                                                   float* __restrict__ Pc,
                                                   float* __restrict__ Qc) {
    __shared__ float ce[NC];
    int bk = blockIdx.x;
    int o = threadIdx.x;  // 384
    if (o < NC) ce[o] = cen[(size_t)bk * NC + o];
    __syncthreads();
    float pc = bc[o], qc = 0.0f;
    for (int c = 0; c < NC; ++c) {
        pc += ce[c] * Wc[(size_t)c * NCOUT + o];
        qc += ce[c] * Wc[(size_t)(NC + c) * NCOUT + o];
    }
    Pc[(size_t)bk * NCOUT + o] = pc;
    Qc[(size_t)bk * NCOUT + o] = qc;
}

// ---------------- cluster message max ----------------
__global__ __launch_bounds__(384) void hcmax_kernel(const float* __restrict__ Pc,
                                                    const float* __restrict__ Qc,
                                                    float* __restrict__ hc) {
    int b = blockIdx.x >> 4, i = blockIdx.x & 15;
    int o = threadIdx.x;
    float pi = Pc[((size_t)b * NK + i) * NCOUT + o];
    float qi = Qc[((size_t)b * NK + i) * NCOUT + o];
    float m = -FLT_INF;
    for (int j = 0; j < NK; ++j) {
        float z = pi - qi + Qc[((size_t)b * NK + j) * NCOUT + o];
        m = fmaxf(m, gelu_t(z));
    }
    hc[((size_t)b * NK + i) * NCOUT + o] = m;
}

// ---------------- node message max + add cluster term (writes hn over P) ----------------
__global__ __launch_bounds__(384) void hv_kernel(float* __restrict__ P,
                                                 const float* __restrict__ Q,
                                                 const int* __restrict__ nbr,
                                                 const int* __restrict__ lsv,
                                                 const float* __restrict__ hc) {
    int i = blockIdx.x;
    int b = blockIdx.y;
    size_t row = (size_t)b * NN + i;
    int o = threadIdx.x;  // 384
    float pi = P[row * NCOUT + o];
    float qi = Q[row * NCOUT + o];
    float m = -FLT_INF;
#pragma unroll
    for (int q = 0; q < KNB; ++q) {
        int j = nbr[row * KNB + q];
        if (j < 0) break;
        float z = pi - qi + Q[((size_t)b * NN + j) * NCOUT + o];
        m = fmaxf(m, gelu_t(z));
    }
    int lab = lsv[row];
    P[row * NCOUT + o] = m + hc[((size_t)b * NK + lab) * NCOUT + o];
}

// ---------------- transpose (b,n,c)->(b,c,n) + residual ----------------
__global__ void out_kernel(const float* __restrict__ T, const float* __restrict__ X,
                           float* __restrict__ Y) {
    __shared__ float t[32][33];
    int b = blockIdx.z;
    int n0 = blockIdx.y * 32, c0 = blockIdx.x * 32;
    int tx = threadIdx.x, ty = threadIdx.y;  // 32 x 8
#pragma unroll
    for (int q = 0; q < 4; ++q) {
        int n = n0 + ty + q * 8;
        t[ty + q * 8][tx] = T[((size_t)b * NN + n) * NC + c0 + tx];
    }
    __syncthreads();
#pragma unroll
    for (int q = 0; q < 4; ++q) {
        int c = c0 + ty + q * 8;
        size_t idx = ((size_t)b * NC + c) * NN + n0 + tx;
        Y[idx] = t[tx][ty + q * 8] + X[idx];
    }
}

extern "C" void kernel_launch(void* const* d_in, const int* in_sizes, int n_in, void* d_out,
                              int out_size, void* d_ws, size_t ws_size, hipStream_t stream) {
    const float* x = (const float*)d_in[0];
    const int* labels = (const int*)d_in[1];
    const float* cpe_w = (const float*)d_in[2];
    const float* cpe_b = (const float*)d_in[3];
    const float* fc1_w = (const float*)d_in[4];
    const float* fc1_b = (const float*)d_in[5];
    const float* nn_v_w = (const float*)d_in[6];
    const float* nn_v_b = (const float*)d_in[7];
    const float* nn_c_w = (const float*)d_in[8];
    const float* nn_c_b = (const float*)d_in[9];
    const float* fc2_w = (const float*)d_in[10];
    const float* fc2_b = (const float*)d_in[11];
    float* out = (float*)d_out;

    const size_t SZ_XS = (size_t)NB * NN * NC;
    const size_t SZ_P = (size_t)NB * NN * NCOUT;
    const size_t BN = (size_t)NB * NN;
    const size_t SZ_CEN = (size_t)NB * NK * NC;
    const size_t SZ_PC = (size_t)NB * NK * NCOUT;

    float* base = (float*)d_ws;
    float* xs = base;
    float* xpe = xs + SZ_XS;
    float* Pb = xpe + SZ_XS;
    float* Qb = Pb + SZ_P;
    float* rinv = Qb + SZ_P;
    float* sqv = rinv + BN;
    float* cen = sqv + BN;
    float* Pc = cen + SZ_CEN;
    float* Qc = Pc + SZ_PC;
    float* hcv = Qc + SZ_PC;
    int* order = (int*)(hcv + SZ_PC);
    int* mapping = order + BN;
    int* lsv = mapping + BN;
    int* nbrv = lsv + BN;
    int* cntk = nbrv + BN * KNB;
    int* offk = cntk + NB * NK;

    hist_kernel<<<NB, 256, 0, stream>>>(labels, cntk, offk);
    order_kernel<<<NB * NK, 64, 0, stream>>>(labels, offk, order, mapping, lsv);
    conv_kernel<<<NB * NC, 256, 0, stream>>>(x, cpe_w, cpe_b, xpe);
    gemm64<true><<<dim3(NC / 64, NN / 64, NB), 256, 0, stream>>>(
        xpe, (size_t)NC * NN, NN, fc1_w, NC, fc1_b, xs, (size_t)NN * NC, NC, mapping, NN, NC);
    norm_kernel<<<(NB * NN) / 4, 256, 0, stream>>>(xs, rinv, sqv);
    knn_kernel<<<dim3((NN + 63) / 64, NK, NB), 256, 0, stream>>>(xs, rinv, sqv, offk, cntk,
                                                                 nbrv);
    gemm64<false><<<dim3(NCOUT / 64, NN / 64, NB), 256, 0, stream>>>(
        xs, (size_t)NN * NC, NC, nn_v_w, NCOUT, nn_v_b, Pb, (size_t)NN * NCOUT, NCOUT, nullptr,
        NN, NC);
    gemm64<false><<<dim3(NCOUT / 64, NN / 64, NB), 256, 0, stream>>>(
        xs, (size_t)NN * NC, NC, nn_v_w + (size_t)NC * NCOUT, NCOUT, nullptr, Qb,
        (size_t)NN * NCOUT, NCOUT, nullptr, NN, NC);
    cen_kernel<<<NB * NK, NC, 0, stream>>>(xs, offk, cntk, cen);
    pcqc_kernel<<<NB * NK, NCOUT, 0, stream>>>(cen, nn_c_w, nn_c_b, Pc, Qc);
    hcmax_kernel<<<NB * NK, NCOUT, 0, stream>>>(Pc, Qc, hcv);
    hv_kernel<<<dim3(NN, NB), NCOUT, 0, stream>>>(Pb, Qb, nbrv, lsv, hcv);
    gemm64<false><<<dim3(NC / 64, NN / 64, NB), 256, 0, stream>>>(
        Pb, (size_t)NN * NCOUT, NCOUT, fc2_w, NC, fc2_b, xpe, (size_t)NN * NC, NC, order, NN,
        NCOUT);
    out_kernel<<<dim3(NC / 32, NN / 32, NB), dim3(32, 8), 0, stream>>>(xpe, x, out);
}